// Round 11
// baseline (208.640 us; speedup 1.0000x reference)
//
#include <hip/hip_runtime.h>

// B=256 queries, D=2048, d=64 hash dim, N=100000 database, C=100 classes,
// K=1000 SMALLEST-sim selection. Inputs f32, labels int, output f32.
//
// Exact-set algorithm (absmax 0 in R2..R10): MFMA f16 screening GEMM, scores
// stored as f16; rigorous bound |v64 - stored_score| <= M =
// 0.5*S*1.1e-3 + (50+0.55S)*2^-10 + 0.05  (S = ||out_b||*max||c||):
//   score < TL = lo_tb - 2M  => certainly in f64 top-K  (label-counted)
//   score > TH = hi_tb + 2M  => certainly out
//   else                     => candidate (~500/row), exact f64 resolve.
//
// R11: hist moved INTO k_sim (scores are already in registers there; R10's
// k_rowall spent a full 51MB pass rebuilding it). LDS per-row hist (R9's
// validated gemmhist consistency: f32-bucket hist + f64 TL/TH edges) merged
// by fire-and-forget global atomics into histg[256x256] (zeroed in k_prep).
// k_rowall: read 1KB hist -> scan -> ONE classify pass -> exact resolve.
//   k_prep  : detect labels dtype + codes f32->f16 + pmax + out=x@W + zero histg
//   k_sim   : MFMA screen -> f16 score store + LDS hist -> histg merge
//   k_rowall: per row: scan -> [TL,TH] -> classify -> f64 resolve -> emit

#define TPB 256
#define TPF 1024         // threads for k_rowall
#define NBK 256          // buckets per row histogram
#define NCHX 128         // code-chunks (grid.x) for k_sim
#define MROWS 32         // out-rows per k_sim block
#define CAPC 2048        // per-row candidate capacity (expected ~500)
#define NCLS 100

typedef _Float16 half8 __attribute__((ext_vector_type(8)));
typedef float floatx4 __attribute__((ext_vector_type(4)));

struct Ptrs {
  const float* x; const float* W; const float* codes;
  const int* labels; const int* Kp;
  double* out64; double* B1sq; unsigned short* out16;
  int* shiftp; float* pmax; unsigned* histg;
  unsigned short* codes16; unsigned short* simh;
  float* outp;
  int B, N, D, Npad, nCvt, gridPrep, cpb;
};

static __device__ __forceinline__ unsigned short f2h(float v) {
  _Float16 h = (_Float16)v; unsigned short u; __builtin_memcpy(&u, &h, 2); return u;
}
static __device__ __forceinline__ float h2f(unsigned short u) {
  _Float16 h; __builtin_memcpy(&h, &u, 2); return (float)h;
}
static __device__ __forceinline__ unsigned packh2(float a, float b) {
  return (unsigned)f2h(a) | ((unsigned)f2h(b) << 16);
}

static __device__ __forceinline__ void rowRange(double b1sq, double cmax,
                                                double& lo, double& inv, double& bw) {
  double hr = 0.5 * sqrt(b1sq * cmax) * 1.000001 + 9.0;  // +9 > M
  lo = 50.0 - hr;
  bw = (2.0 * hr) / (double)NBK;
  inv = (double)NBK / (2.0 * hr);
}

static __device__ __forceinline__ double dot1(const float* __restrict__ codes, int n,
                                              const double* __restrict__ od) {
  const float4* crow = (const float4*)(codes + (size_t)n * 64);
  double a = 0.0;
#pragma unroll
  for (int i = 0; i < 16; ++i) {
    float4 q = crow[i];
    a = fma((double)q.x, od[i*4+0], a);
    a = fma((double)q.y, od[i*4+1], a);
    a = fma((double)q.z, od[i*4+2], a);
    a = fma((double)q.w, od[i*4+3], a);
  }
  return a;
}

// MFMA A-fragment loader (mfma_f32_16x16x32_f16, m89-verified family):
//   A: lane holds A[m=lane&15][k=(lane>>4)*8+j]; D: reg r = D[(lane>>4)*4+r][lane&15]
static __device__ __forceinline__ void loadA(const unsigned short* __restrict__ out16,
                                             int m0, int mr, int quad,
                                             half8& a00, half8& a01, half8& a10, half8& a11) {
  const uint4* o4 = (const uint4*)out16;
  uint4 u;
  u = o4[(size_t)(m0 + mr) * 8 + quad];          __builtin_memcpy(&a00, &u, 16);
  u = o4[(size_t)(m0 + mr) * 8 + 4 + quad];      __builtin_memcpy(&a01, &u, 16);
  u = o4[(size_t)(m0 + 16 + mr) * 8 + quad];     __builtin_memcpy(&a10, &u, 16);
  u = o4[(size_t)(m0 + 16 + mr) * 8 + 4 + quad]; __builtin_memcpy(&a11, &u, 16);
}

// ================= k_prep: detect + cvt/norm + out-GEMM + zero histg =========
__global__ __launch_bounds__(TPB) void k_prep(Ptrs P) {
  __shared__ union { float fred[TPB]; double dred[TPB]; } sm;
  __shared__ int flag;
  int bid = blockIdx.x, tid = threadIdx.x;
  for (int i = bid * TPB + tid; i < P.B * NBK; i += P.gridPrep * TPB)
    P.histg[i] = 0u;
  if (bid < P.nCvt) {                       // ---- codes f32->f16 + per-block max norm
    float m = 0.0f;
    int n = bid * TPB + tid;
    if (n < P.N) {
      const float4* crow = (const float4*)(P.codes + (size_t)n * 64);
      uint4* orow = (uint4*)(P.codes16 + (size_t)n * 64);
      double c2 = 0.0;
#pragma unroll
      for (int i = 0; i < 8; ++i) {
        float4 qa = crow[2*i], qb = crow[2*i+1];
        c2 = fma((double)qa.x,(double)qa.x,c2); c2 = fma((double)qa.y,(double)qa.y,c2);
        c2 = fma((double)qa.z,(double)qa.z,c2); c2 = fma((double)qa.w,(double)qa.w,c2);
        c2 = fma((double)qb.x,(double)qb.x,c2); c2 = fma((double)qb.y,(double)qb.y,c2);
        c2 = fma((double)qb.z,(double)qb.z,c2); c2 = fma((double)qb.w,(double)qb.w,c2);
        uint4 o;
        o.x = packh2(qa.x, qa.y); o.y = packh2(qa.z, qa.w);
        o.z = packh2(qb.x, qb.y); o.w = packh2(qb.z, qb.w);
        orow[i] = o;
      }
      m = (float)(c2 * 1.000001);
    } else if (n < P.Npad) {
      uint4* orow = (uint4*)(P.codes16 + (size_t)n * 64);
      uint4 z = {0u,0u,0u,0u};
#pragma unroll
      for (int i = 0; i < 8; ++i) orow[i] = z;
    }
    sm.fred[tid] = m; __syncthreads();
    for (int off = 128; off > 0; off >>= 1) {
      if (tid < off) sm.fred[tid] = fmaxf(sm.fred[tid], sm.fred[tid + off]);
      __syncthreads();
    }
    if (tid == 0) P.pmax[bid] = sm.fred[0];
  } else if (bid < P.nCvt + P.B) {          // ---- out row b = x@W (f64 + f16)
    if (tid == 0) P.pmax[bid] = 0.0f;
    int b = bid - P.nCvt;
    int t = tid & 63, w = tid >> 6;        // 4 K-chunks x 8 accumulators
    int kc = P.D >> 2;
    const float* xr = P.x + (size_t)b * P.D;
    double a[8];
#pragma unroll
    for (int j = 0; j < 8; ++j) a[j] = 0.0;
    for (int k = w * kc; k < (w + 1) * kc; k += 8) {
      float4 xv0 = *(const float4*)(xr + k);
      float4 xv1 = *(const float4*)(xr + k + 4);
      float xs[8] = {xv0.x, xv0.y, xv0.z, xv0.w, xv1.x, xv1.y, xv1.z, xv1.w};
#pragma unroll
      for (int j = 0; j < 8; ++j)
        a[j] = fma((double)xs[j], (double)P.W[(size_t)(k + j) * 64 + t], a[j]);
    }
    sm.dred[tid] = ((a[0]+a[1])+(a[2]+a[3])) + ((a[4]+a[5])+(a[6]+a[7]));
    __syncthreads();
    double o = 0.0;
    if (w == 0) {
      o = sm.dred[t] + sm.dred[64+t] + sm.dred[128+t] + sm.dred[192+t];
      P.out64[(size_t)b * 64 + t] = o;
      P.out16[(size_t)b * 64 + t] = f2h((float)o);
    }
    __syncthreads();
    if (w == 0) sm.dred[t] = o * o;
    __syncthreads();
    if (tid == 0) {
      double s = 0.0;
      for (int i = 0; i < 64; ++i) s += sm.dred[i];
      P.B1sq[b] = s;
    }
  } else {                                  // ---- detect labels dtype
    if (tid == 0) { P.pmax[bid] = 0.0f; flag = 0; }
    __syncthreads();
    int mm = P.N < 256 ? P.N : 256;
    if (tid < mm && P.labels[2 * tid + 1] != 0) atomicOr(&flag, 1);
    __syncthreads();
    if (tid == 0) *P.shiftp = flag ? 0 : 1;  // label(n) = labels[n << shift]
  }
}

// ==== k_sim: MFMA screen -> f16 score store + LDS hist -> histg merge ========
__global__ __launch_bounds__(TPB) void k_sim(Ptrs P) {
  __shared__ unsigned hist[MROWS * NBK];     // 32 KB
  __shared__ float sP[MROWS], sQ[MROWS], scr[TPB];
  int tid = threadIdx.x;
  int cx = blockIdx.x, m0 = blockIdx.y * MROWS;
  // cmax from pmax slots
  float m = 0.0f;
  for (int i = tid; i < P.gridPrep; i += TPB) m = fmaxf(m, P.pmax[i]);
  scr[tid] = m; __syncthreads();
  for (int off = 128; off > 0; off >>= 1) {
    if (tid < off) scr[tid] = fmaxf(scr[tid], scr[tid + off]);
    __syncthreads();
  }
  float cmax = scr[0];
  for (int i = tid; i < MROWS * NBK; i += TPB) hist[i] = 0u;
  if (tid < MROWS) {
    double lo, inv, bw;
    rowRange(P.B1sq[m0 + tid], (double)cmax, lo, inv, bw);
    sP[tid] = (float)(-0.5 * inv);           // bucket = trunc(d*P + Q), monotone
    sQ[tid] = (float)((50.0 - lo) * inv);
  }
  __syncthreads();
  int l = tid & 63, w = tid >> 6, quad = l >> 4, mr = l & 15;
  half8 a00, a01, a10, a11;
  loadA(P.out16, m0, mr, quad, a00, a01, a10, a11);
  float Pv0[4], Qv0[4], Pv1[4], Qv1[4];
#pragma unroll
  for (int r = 0; r < 4; ++r) {
    Pv0[r] = sP[quad*4 + r];      Qv0[r] = sQ[quad*4 + r];
    Pv1[r] = sP[16 + quad*4 + r]; Qv1[r] = sQ[16 + quad*4 + r];
  }
  int cstart = cx * P.cpb;
  int cend = cstart + P.cpb; if (cend > P.N) cend = P.N;
  const uint4* c4 = (const uint4*)P.codes16;
  floatx4 z = {0.f, 0.f, 0.f, 0.f};
  for (int base = cstart; base < cend; base += 64) {
    int nrow = base + w * 16 + mr;
    int nc = nrow < P.Npad ? nrow : P.Npad - 1;
    uint4 ub0 = c4[(size_t)nc * 8 + quad];
    uint4 ub1 = c4[(size_t)nc * 8 + 4 + quad];
    half8 b0, b1;
    __builtin_memcpy(&b0, &ub0, 16); __builtin_memcpy(&b1, &ub1, 16);
    floatx4 d0 = __builtin_amdgcn_mfma_f32_16x16x32_f16(a00, b0, z, 0, 0, 0);
    d0 = __builtin_amdgcn_mfma_f32_16x16x32_f16(a01, b1, d0, 0, 0, 0);
    floatx4 d1 = __builtin_amdgcn_mfma_f32_16x16x32_f16(a10, b0, z, 0, 0, 0);
    d1 = __builtin_amdgcn_mfma_f32_16x16x32_f16(a11, b1, d1, 0, 0, 0);
    if (nrow < P.N) {
#pragma unroll
      for (int r = 0; r < 4; ++r) {
        P.simh[(size_t)(m0 + quad*4 + r) * P.N + nrow] = f2h(fmaf(d0[r], -0.5f, 50.0f));
        int bk0 = (int)fmaf(d0[r], Pv0[r], Qv0[r]);
        bk0 = bk0 < 0 ? 0 : (bk0 > NBK-1 ? NBK-1 : bk0);
        atomicAdd(&hist[(quad*4 + r) * NBK + bk0], 1u);     // LDS
        P.simh[(size_t)(m0 + 16 + quad*4 + r) * P.N + nrow] = f2h(fmaf(d1[r], -0.5f, 50.0f));
        int bk1 = (int)fmaf(d1[r], Pv1[r], Qv1[r]);
        bk1 = bk1 < 0 ? 0 : (bk1 > NBK-1 ? NBK-1 : bk1);
        atomicAdd(&hist[(16 + quad*4 + r) * NBK + bk1], 1u);
      }
    }
  }
  __syncthreads();
  // fire-and-forget merge (no return -> no wave stall; R6..R10 pattern)
  for (int i = tid; i < MROWS * NBK; i += TPB) {
    unsigned c = hist[i];
    if (c) atomicAdd(&P.histg[(m0 + (i >> 8)) * NBK + (i & (NBK - 1))], c);
  }
}

// ==== k_rowall: per row: scan -> classify (one pass) -> f64 resolve -> emit ==
__global__ __launch_bounds__(TPF) void k_rowall(Ptrs P) {
  __shared__ double key[CAPC];              // 16 KB
  __shared__ int kidx[CAPC];                // 8 KB
  __shared__ unsigned hist[NBK];
  __shared__ unsigned lab[NCLS];
  __shared__ float scr[TPF];
  __shared__ float sTL, sTH;
  __shared__ unsigned cnt_s;
  int b = blockIdx.x, tid = threadIdx.x;
  // ---- cmax from pmax slots ----
  float m = 0.0f;
  for (int i = tid; i < P.gridPrep; i += TPF) m = fmaxf(m, P.pmax[i]);
  scr[tid] = m; __syncthreads();
  for (int off = TPF / 2; off > 0; off >>= 1) {
    if (tid < off) scr[tid] = fmaxf(scr[tid], scr[tid + off]);
    __syncthreads();
  }
  float cmax = scr[0];
  double lo, inv, bw;
  rowRange(P.B1sq[b], (double)cmax, lo, inv, bw);
  if (tid < NBK) hist[tid] = P.histg[b * NBK + tid];
  for (int i = tid; i < NCLS; i += TPF) lab[i] = 0u;
  if (tid == 0) cnt_s = 0u;
  __syncthreads();
  // ---- inclusive scan (first 256 threads) -> threshold bucket -> [TL,TH] ----
  for (int off = 1; off < NBK; off <<= 1) {
    unsigned add = (tid < NBK && tid >= off) ? hist[tid - off] : 0u;
    __syncthreads();
    if (tid < NBK) hist[tid] += add;
    __syncthreads();
  }
  unsigned K = (unsigned)P.Kp[0];
  if (tid < NBK) {
    unsigned cum = hist[tid], prev = tid ? hist[tid - 1] : 0u;
    if (cum >= K && prev < K) {             // exactly one thread: tb = tid
      double S = sqrt(P.B1sq[b] * (double)cmax);
      // M: f16 input cvt + f32 accum + f16 STORE quantization (2x slack each)
      double M = 0.5 * S * 1.1e-3 + (50.0 + 0.55 * S) * 0x1p-10 + 0.05;
      double lot = lo + (double)tid * bw;
      sTL = (float)(lot - 2.0 * M - 1e-3);
      sTH = (float)(lot + bw + 2.0 * M + 1e-3);
    }
  }
  __syncthreads();
  float TL = sTL, TH = sTH;
  int shift = *P.shiftp;
  // ---- classify (single pass: below -> lab, band -> candidate list) ----
  const unsigned short* rp = P.simh + (size_t)b * P.N;
  const uint4* rp4 = (const uint4*)rp;
  int nu4 = P.N >> 3;
  for (int i = tid; i < nu4; i += TPF) {
    uint4 u = rp4[i];
    unsigned uu[4] = {u.x, u.y, u.z, u.w};
#pragma unroll
    for (int k = 0; k < 8; ++k) {
      float v = h2f((unsigned short)((uu[k >> 1] >> ((k & 1) * 16)) & 0xFFFFu));
      if (v < TL) {
        atomicAdd(&lab[P.labels[(size_t)(i*8 + k) << shift]], 1u);
      } else if (v <= TH) {
        unsigned pos = atomicAdd(&cnt_s, 1u);
        if (pos < CAPC) kidx[pos] = i*8 + k;
      }
    }
  }
  for (int n = (nu4 << 3) + tid; n < P.N; n += TPF) {
    float v = h2f(rp[n]);
    if (v < TL) {
      atomicAdd(&lab[P.labels[(size_t)n << shift]], 1u);
    } else if (v <= TH) {
      unsigned pos = atomicAdd(&cnt_s, 1u);
      if (pos < CAPC) kidx[pos] = n;
    }
  }
  __syncthreads();
  // ---- btot, exact f64 keys, bitonic sort ----
  unsigned bt = 0;
  for (int i = tid; i < NCLS; i += TPF) bt += lab[i];
  scr[tid] = (float)bt; __syncthreads();
  for (int off = TPF / 2; off > 0; off >>= 1) {
    if (tid < off) scr[tid] += scr[tid + off];
    __syncthreads();
  }
  int btot = (int)scr[0];
  int cnt = (int)cnt_s; if (cnt > CAPC) cnt = CAPC;
  int need = (int)K - btot;
  int M2 = 1; while (M2 < cnt) M2 <<= 1;
  const double* od = P.out64 + (size_t)b * 64;
  for (int i = tid; i < M2; i += TPF) {
    if (i < cnt) {
      key[i] = fma(dot1(P.codes, kidx[i], od), -0.5, 50.0);
    } else { key[i] = __builtin_inf(); kidx[i] = 0x7FFFFFFF; }
  }
  __syncthreads();
  for (int size = 2; size <= M2; size <<= 1) {
    for (int stride = size >> 1; stride > 0; stride >>= 1) {
      for (int i = tid; i < M2; i += TPF) {
        int j = i ^ stride;
        if (j > i) {
          double ki = key[i], kj = key[j];
          int ii = kidx[i], ij = kidx[j];
          bool up = ((i & size) == 0);
          bool sw = up ? (kj < ki || (kj == ki && ij < ii))
                       : (kj > ki || (kj == ki && ij > ii));
          if (sw) { key[i] = kj; key[j] = ki; kidx[i] = ij; kidx[j] = ii; }
        }
      }
      __syncthreads();
    }
  }
  // ---- take the quota into lab (lab already holds below counts), emit ----
  int take = need < cnt ? need : cnt;
  if (take < 0) take = 0;
  for (int i = tid; i < take; i += TPF)
    atomicAdd(&lab[P.labels[(size_t)kidx[i] << shift]], 1u);
  __syncthreads();
  double Kd = (double)K;
  for (int c = tid; c < NCLS; c += TPF)
    P.outp[b * NCLS + c] = (float)((double)lab[c] / Kd);
}

extern "C" void kernel_launch(void* const* d_in, const int* in_sizes, int n_in,
                              void* d_out, int out_size, void* d_ws, size_t ws_size,
                              hipStream_t stream) {
  Ptrs P;
  P.x      = (const float*)d_in[0];
  P.W      = (const float*)d_in[1];
  P.codes  = (const float*)d_in[2];
  P.labels = (const int*)d_in[3];
  P.Kp     = (const int*)d_in[4];
  P.B    = out_size / NCLS;                 // 256
  P.N    = in_sizes[3];                     // 100000
  P.D    = in_sizes[0] / P.B;               // 2048
  P.Npad = (P.N + 255) & ~255;              // 100096
  P.nCvt = P.Npad / 256;                    // 391
  P.gridPrep = P.nCvt + P.B + 1;            // cvt + out-rows + detect = 648
  P.cpb  = (((P.Npad + NCHX - 1) / NCHX) + 63) & ~63;  // 832
  P.outp = (float*)d_out;

  char* p = (char*)d_ws;
  P.out64    = (double*)p;         p += (size_t)P.B * 64 * sizeof(double);        // 128 KB
  P.out16    = (unsigned short*)p; p += (size_t)P.B * 64 * 2;                     // 32 KB
  P.B1sq     = (double*)p;         p += (size_t)P.B * sizeof(double);             // 2 KB
  P.shiftp   = (int*)p;            p += 64;
  P.pmax     = (float*)p;          p += 4096;                                     // 4 KB
  P.histg    = (unsigned*)p;       p += (size_t)P.B * NBK * sizeof(unsigned);     // 256 KB
  P.codes16  = (unsigned short*)p; p += (size_t)P.Npad * 64 * 2;                  // 12.8 MB
  P.simh     = (unsigned short*)p;                                                // 51.2 MB

  k_prep<<<P.gridPrep, TPB, 0, stream>>>(P);
  k_sim<<<dim3(NCHX, P.B / MROWS), TPB, 0, stream>>>(P);
  k_rowall<<<P.B, TPF, 0, stream>>>(P);
}